// Round 19
// baseline (2931.268 us; speedup 1.0000x reference)
//
#include <hip/hip_runtime.h>

// GRU decoder, B=256, H=512, T=512. 16 groups x 16 members = 256 WGs (1/CU).
// Round-19: TAGGED-SWEEP exchange -- no flags at all. Each exported 32-bit
// word = {tag16=t+1 | bf16 payload}; u64 stores are single-copy atomic, so
// readiness is certified per-word. Consumers sweep AFTER the local barrier
// drain (members mutually synced => peers' drains ~simultaneous => first
// sweep almost always succeeds); failed words retried individually (cheap).
// Detect+reload = ONE coherence trip (r11 paid two: flag-detect + reload).
// TPB=512: 512 lanes sweep 4096 u64 at 8 named u64/lane (r17: >8 chunks).
// Out-store issues in the NEXT iteration's phase-1 (gates waves idle there),
// acked inside barrier-2's existing export-drain window. r12/r13 lesson kept:
// readiness (tags) is part of the data itself, never signaled early.

typedef __attribute__((ext_vector_type(8))) short short8;
typedef __attribute__((ext_vector_type(4))) float f32x4;
typedef __attribute__((ext_vector_type(4))) unsigned int u32x4;
typedef unsigned short ushort_t;
typedef unsigned int uint_t;
typedef unsigned long long u64_t;

#define NG 16
#define NM 16
#define NB 16
#define NJ 32
#define TPB 512
#define RETRY_MAX 16384u
#define ABORT_IDX 8192  // u32 idx (byte 32768) in control region
#define GBUF_BASE 16384 // u32 idx of data region (byte 65536)
#define PAR_U64 65536   // u64 per parity: 16 groups * 16 members * 256
#define GRP_U64 4096    // u64 per group

#define ALD(P) __hip_atomic_load((P), __ATOMIC_RELAXED, __HIP_MEMORY_SCOPE_AGENT)
#define AST(P, V) __hip_atomic_store((P), (V), __ATOMIC_RELAXED, __HIP_MEMORY_SCOPE_AGENT)

__device__ __forceinline__ ushort_t bf16_rne(float f) {
  uint_t u = __float_as_uint(f);
  return (ushort_t)((u + 0x7fffu + ((u >> 16) & 1u)) >> 16);
}
__device__ __forceinline__ float bf16f(ushort_t h) {
  return __uint_as_float(((uint_t)h) << 16);
}
__device__ __forceinline__ int tagok(u64_t q, uint_t tag) {
  return (((uint_t)(q >> 16) & 0xFFFFu) == tag) &&
         ((uint_t)(q >> 48) == tag);
}
__device__ __forceinline__ int gRow(int rs, int m) {
  int base = m * NJ;
  if (rs < 32) return base + rs;
  if (rs < 64) return 512 + base + (rs - 32);
  return 1024 + base + (rs - 64);
}

template <bool LO>
__device__ __forceinline__ void loadW(short8* dst, const float* __restrict__ W,
                                      int tile, int m, int lane) {
  int rs = tile * 16 + (lane & 15);
  const float* p = W + (size_t)gRow(rs, m) * 512 + ((lane >> 4) << 3);
#pragma unroll
  for (int c = 0; c < 16; ++c) {
    const float* pc = p + c * 32;
    short8 o;
#pragma unroll
    for (int i = 0; i < 8; ++i) {
      float v = pc[i];
      ushort_t hi = bf16_rne(v);
      o[i] = LO ? (short)bf16_rne(v - bf16f(hi)) : (short)hi;
    }
    dst[c] = o;
  }
}

__global__ __launch_bounds__(TPB, 1) void gru_kernel(
    const float* __restrict__ x, const float* __restrict__ Wih,
    const float* __restrict__ Whh, const float* __restrict__ bih,
    const float* __restrict__ bhh, float* __restrict__ out,
    uint_t* __restrict__ wsp, int NT) {
  __shared__ __align__(16) uint_t s_pb[4096];  // 16KB: 16 chunks x 1KB (hi)
  __shared__ __align__(16) uint_t s_xlo[4096]; // x lo-planes (gi phase only)
  __shared__ float s_gi[96 * 17];
  __shared__ float s_gh[96 * 17];
  __shared__ float s_hloc[NB * NJ]; // own h slice, f32 across steps
  __shared__ float s_bhh[NJ];
  __shared__ int s_stop;

  const int tid = threadIdx.x;
  const int lane = tid & 63;
  const int w = tid >> 6;
  const int bid = blockIdx.x;
  const int g = bid & 15;
  const int m = bid >> 4;
  if (NT <= 0) return;

  uint_t* flagsu = wsp; // abort flag only
  u64_t* gq = (u64_t*)(wsp + GBUF_BASE);

  // ---- stage relu(x) as hi plane (s_pb) + lo plane (s_xlo) ----
  for (int i = tid; i < 1024; i += TPB) {
    int b = i >> 6, k0 = (i & 63) << 3;
    const float* px = x + (size_t)(g * NB + b) * 512 + k0;
    u32x4 vh, vl;
#pragma unroll
    for (int jj = 0; jj < 4; ++jj) {
      float f0 = px[2 * jj], f1 = px[2 * jj + 1];
      f0 = f0 > 0.f ? f0 : 0.f;
      f1 = f1 > 0.f ? f1 : 0.f;
      ushort_t h0 = bf16_rne(f0), h1 = bf16_rne(f1);
      vh[jj] = (uint_t)h0 | ((uint_t)h1 << 16);
      vl[jj] = (uint_t)bf16_rne(f0 - bf16f(h0)) |
               ((uint_t)bf16_rne(f1 - bf16f(h1)) << 16);
    }
    int c = k0 >> 5, kk = k0 & 31;
    int base = c * 1024 + ((((b << 6) + (kk << 1))) ^ ((b & 7) << 4));
    *(u32x4*)((char*)s_pb + base) = vh;
    *(u32x4*)((char*)s_xlo + base) = vl;
  }
  if (tid < NJ) s_bhh[tid] = bhh[1024 + m * NJ + tid];
  if (tid == 0) s_stop = 0;
  __syncthreads();

  short8 wA[16], wB[16];
  const f32x4 vzero = {0.f, 0.f, 0.f, 0.f};
  const int bcol = lane & 15;
  const int roff = ((bcol << 6) + ((lane >> 4) << 4)) ^ ((bcol & 7) << 4);
  const char* pb = (const char*)s_pb;
  const char* pxl = (const char*)s_xlo;

  // ---- gi = relu(x) @ W_ih^T (3-term hi/lo split) ----
  f32x4 acc0 = vzero, acc1 = vzero;
  if (w < 3) {
    loadW<false>(wA, Wih, 2 * w, m, lane);
    loadW<false>(wB, Wih, 2 * w + 1, m, lane);
    {
      f32x4 a0h = vzero, a0l = vzero, a1h = vzero, a1l = vzero;
#pragma unroll
      for (int c = 0; c < 16; ++c) {
        short8 bh = *(const short8*)(pb + c * 1024 + roff);
        short8 bl = *(const short8*)(pxl + c * 1024 + roff);
        a0h = __builtin_amdgcn_mfma_f32_16x16x32_bf16(wA[c], bh, a0h, 0, 0, 0);
        a1h = __builtin_amdgcn_mfma_f32_16x16x32_bf16(wB[c], bh, a1h, 0, 0, 0);
        a0l = __builtin_amdgcn_mfma_f32_16x16x32_bf16(wA[c], bl, a0l, 0, 0, 0);
        a1l = __builtin_amdgcn_mfma_f32_16x16x32_bf16(wB[c], bl, a1l, 0, 0, 0);
      }
      acc0 = a0h + a0l;
      acc1 = a1h + a1l;
    }
    loadW<true>(wA, Wih, 2 * w, m, lane);
    loadW<true>(wB, Wih, 2 * w + 1, m, lane);
#pragma unroll
    for (int c = 0; c < 16; ++c) {
      short8 bh = *(const short8*)(pb + c * 1024 + roff);
      acc0 = __builtin_amdgcn_mfma_f32_16x16x32_bf16(wA[c], bh, acc0, 0, 0, 0);
      acc1 = __builtin_amdgcn_mfma_f32_16x16x32_bf16(wB[c], bh, acc1, 0, 0, 0);
    }
  }
  __syncthreads();
  if (w < 3) {
    int drow = (lane >> 4) << 2;
#pragma unroll
    for (int q = 0; q < 4; ++q) {
      int rs0 = 2 * w * 16 + drow + q, rs1 = rs0 + 16;
      int g0 = gRow(rs0, m), g1 = gRow(rs1, m);
      s_gi[rs0 * 17 + bcol] = acc0[q] + bih[g0] + (rs0 < 64 ? bhh[g0] : 0.f);
      s_gi[rs1 * 17 + bcol] = acc1[q] + bih[g1] + (rs1 < 64 ? bhh[g1] : 0.f);
    }
    loadW<false>(wA, Whh, 2 * w, m, lane); // W_hh resident from here
    loadW<false>(wB, Whh, 2 * w + 1, m, lane);
  }
  for (int i = tid; i < 4096; i += TPB) s_pb[i] = 0u; // h0 = 0
  for (int i = tid; i < NB * NJ; i += TPB) s_hloc[i] = 0.f;
  __syncthreads();

  const size_t outRow = (size_t)NT * 512;
  float* outBase = out + (size_t)(g * NB) * outRow + m * NJ;

  // sweep lane mapping (all 512 threads): 8 contiguous u64 per lane
  const int pp = tid >> 5;           // peer 0..15
  const int sb = tid & 31;
  const int sbb = sb >> 1;           // row b
  const int kq0 = (sb & 1) << 3;     // u64 slot base within row
  const int et = tid - 256;          // gates threads: waves 4-5 (et in [0,128))
  const int isg = ((unsigned)et < 128u);
  const int gb = et >> 3, gj0 = (et & 7) << 2;

  f32x4 pout = vzero;
  int lastT = -1;

  for (int t = 0; t < NT; ++t) {
    const int xpar = (t + 1) & 1;
    // ---- gates waves: issue PREVIOUS step's out-store (overlaps phase 1;
    //      its HBM ack drains inside barrier#2's export-drain window) ----
    if (isg && lastT >= 0) {
      __builtin_nontemporal_store(
          pout, (f32x4*)(outBase + (size_t)gb * outRow +
                         (size_t)lastT * 512 + gj0));
    }
    // ---- phase 1: gh = W_hh @ h_hi from LDS chunks (waves 0-2) ----
    if (w < 3) {
      f32x4 aE0 = vzero, aO0 = vzero, aE1 = vzero, aO1 = vzero;
#pragma unroll
      for (int p = 0; p < 16; p += 2) {
        short8 b0 = *(const short8*)(pb + p * 1024 + roff);
        short8 b1 = *(const short8*)(pb + (p + 1) * 1024 + roff);
        aE0 = __builtin_amdgcn_mfma_f32_16x16x32_bf16(wA[p], b0, aE0, 0, 0, 0);
        aE1 = __builtin_amdgcn_mfma_f32_16x16x32_bf16(wB[p], b0, aE1, 0, 0, 0);
        aO0 = __builtin_amdgcn_mfma_f32_16x16x32_bf16(wA[p + 1], b1, aO0, 0, 0, 0);
        aO1 = __builtin_amdgcn_mfma_f32_16x16x32_bf16(wB[p + 1], b1, aO1, 0, 0, 0);
      }
      f32x4 r0 = aE0 + aO0, r1 = aE1 + aO1;
      int drow = (lane >> 4) << 2;
#pragma unroll
      for (int q = 0; q < 4; ++q) {
        s_gh[(2 * w * 16 + drow + q) * 17 + bcol] = r0[q];
        s_gh[((2 * w + 1) * 16 + drow + q) * 17 + bcol] = r1[q];
      }
    }
    __syncthreads(); // barrier #1: s_gh ready; s_pb free for this step's sweep

    // ---- gates (waves 4-5): h(t+1) in regs; tagged export ----
    if (isg) {
      float hn[4];
#pragma unroll
      for (int e = 0; e < 4; ++e) {
        int j = gj0 + e;
        float pr = s_gi[j * 17 + gb] + s_gh[j * 17 + gb];
        float pz = s_gi[(32 + j) * 17 + gb] + s_gh[(32 + j) * 17 + gb];
        float r = 1.f / (1.f + __expf(-pr));
        float z = 1.f / (1.f + __expf(-pz));
        float pn = s_gi[(64 + j) * 17 + gb] +
                   r * (s_gh[(64 + j) * 17 + gb] + s_bhh[j]);
        float n = 1.f - 2.f / (1.f + __expf(2.f * pn));
        hn[e] = n + z * (s_hloc[gb * 32 + j] - n);
        s_hloc[gb * 32 + j] = hn[e];
      }
      pout = (f32x4){hn[0], hn[1], hn[2], hn[3]};
      lastT = t;
      if (t + 1 < NT) {
        const uint_t tg = (uint_t)(t + 1) << 16;
        uint_t w0 = (uint_t)bf16_rne(hn[0]) | tg;
        uint_t w1 = (uint_t)bf16_rne(hn[1]) | tg;
        uint_t w2 = (uint_t)bf16_rne(hn[2]) | tg;
        uint_t w3 = (uint_t)bf16_rne(hn[3]) | tg;
        u64_t* dst = gq + (size_t)xpar * PAR_U64 + g * GRP_U64 + (m << 8) +
                     (gb << 4) + ((et & 7) << 1);
        AST(dst, (u64_t)w0 | ((u64_t)w1 << 32));
        AST(dst + 1, (u64_t)w2 | ((u64_t)w3 << 32));
      }
    }
    __syncthreads(); // barrier #2: drains exports (and prev out-store)

    // ---- tagged sweep (ALL 512 threads): one trip detect+reload ----
    if (t + 1 < NT) {
      const uint_t tag = (uint_t)(t + 1);
      const u64_t* src = gq + (size_t)xpar * PAR_U64 + g * GRP_U64 +
                         (pp << 8) + (sbb << 4) + kq0;
      u64_t q0 = ALD(src + 0), q1 = ALD(src + 1), q2 = ALD(src + 2),
            q3 = ALD(src + 3), q4 = ALD(src + 4), q5 = ALD(src + 5),
            q6 = ALD(src + 6), q7 = ALD(src + 7);
      uint_t att = 0;
      int good = 0;
      for (;;) {
        uint_t mk = (tagok(q0, tag) ? 1u : 0u) | (tagok(q1, tag) ? 2u : 0u) |
                    (tagok(q2, tag) ? 4u : 0u) | (tagok(q3, tag) ? 8u : 0u) |
                    (tagok(q4, tag) ? 16u : 0u) | (tagok(q5, tag) ? 32u : 0u) |
                    (tagok(q6, tag) ? 64u : 0u) | (tagok(q7, tag) ? 128u : 0u);
        if (__all((int)(mk == 255u))) {
          good = 1;
          break;
        }
        ++att;
        uint_t ab = 0;
        if ((att & 7u) == 0u) {
          ab = ALD(&flagsu[ABORT_IDX]);
          if (att > RETRY_MAX) {
            AST(&flagsu[ABORT_IDX], 1u);
            ab = 1;
          }
        }
        if (__any((int)(ab != 0))) {
          if (lane == 0) s_stop = 1;
          break;
        }
        __builtin_amdgcn_s_sleep(2);
        if (!(mk & 1u)) q0 = ALD(src + 0);
        if (!(mk & 2u)) q1 = ALD(src + 1);
        if (!(mk & 4u)) q2 = ALD(src + 2);
        if (!(mk & 8u)) q3 = ALD(src + 3);
        if (!(mk & 16u)) q4 = ALD(src + 4);
        if (!(mk & 32u)) q5 = ALD(src + 5);
        if (!(mk & 64u)) q6 = ALD(src + 6);
        if (!(mk & 128u)) q7 = ALD(src + 7);
      }
      if (good) { // strip tags, write packed bf16 pairs to swizzled LDS
        char* dstc = (char*)s_pb + pp * 1024;
#define STW(k, qq)                                                             \
  {                                                                            \
    uint_t pk = ((uint_t)(qq) & 0xFFFFu) |                                     \
                (((uint_t)((qq) >> 32) & 0xFFFFu) << 16);                      \
    *(uint_t*)(dstc + ((((sbb << 6) + ((kq0 + (k)) << 2)) ^                    \
                        ((sbb & 7) << 4)))) = pk;                              \
  }
        STW(0, q0) STW(1, q1) STW(2, q2) STW(3, q3)
        STW(4, q4) STW(5, q5) STW(6, q6) STW(7, q7)
#undef STW
      }
    }
    __syncthreads(); // barrier #3
    if (s_stop) break;
  }
  // final step's out-store (its ack drains at kernel end)
  if (isg && lastT >= 0) {
    __builtin_nontemporal_store(
        pout,
        (f32x4*)(outBase + (size_t)gb * outRow + (size_t)lastT * 512 + gj0));
  }
}

extern "C" void kernel_launch(void* const* d_in, const int* in_sizes, int n_in,
                              void* d_out, int out_size, void* d_ws,
                              size_t ws_size, hipStream_t stream) {
  const float* x = (const float*)d_in[0];
  const float* Wih = (const float*)d_in[1];
  const float* Whh = (const float*)d_in[2];
  const float* bih = (const float*)d_in[3];
  const float* bhh = (const float*)d_in[4];
  float* out = (float*)d_out;
  int NT = out_size / (256 * 512);
  // ws: [0,64KB) control (abort @32KB; tags self-validate -> no data zeroing);
  // data @64KB: 2 parities x 512KB tagged exchange.
  uint_t* wsp = (uint_t*)d_ws;
  (void)hipMemsetAsync(d_ws, 0, 65536, stream);
  hipLaunchKernelGGL(gru_kernel, dim3(NG * NM), dim3(TPB), 0, stream, x, Wih,
                     Whh, bih, bhh, out, wsp, NT);
}

// Round 20
// 1163.208 us; speedup vs baseline: 2.5200x; 2.5200x over previous
//
#include <hip/hip_runtime.h>

// GRU decoder, B=256, H=512, T=512. 16 groups x 16 members = 256 WGs (1/CU).
// FINAL = round-11 restored verbatim (proven best: 1161us, absmax 3.9e-3).
// Structure: relaxed-agent (sc1) exchange; h as bf16-HI only (state f32);
// per step: MFMA from LDS chunks -> gates -> export -> barrier drain ->
// flag -> out-store overlapping fused poll+reload (waves 0-3 own 4 peers
// each) -> barrier. Three coherence-point RTTs/step = measured floor:
// r12-r19 alternatives (csum flags, tagged data, direct-reg batch, per-wave
// drain, tagged sweep) all regressed -- early-readiness races, reg spills
// vs 128 resident W-VGPRs, or poll contention. sc0 XCD-local exchange
// deadlocks in steady state (r9/r10). Bounded spin + abort cascade kept.

typedef __attribute__((ext_vector_type(8))) short short8;
typedef __attribute__((ext_vector_type(4))) float f32x4;
typedef __attribute__((ext_vector_type(4))) unsigned int u32x4;
typedef unsigned short ushort_t;
typedef unsigned int uint_t;
typedef unsigned long long u64_t;

#define NG 16
#define NM 16
#define NB 16
#define NJ 32
#define TPB 384
#define SPIN_MAX (1u << 16)
#define ABORT_IDX 8192  // u32 idx: abort flag (flags region is 32KB)
#define GBUF_BASE 16384 // u32 idx of data region (byte 65536)
#define GRP_U32 4096    // per group per parity: 16 members * 256 u32 (hi only)
#define BUF_U32 65536   // per parity: 16 groups

#define ALD(P) __hip_atomic_load((P), __ATOMIC_RELAXED, __HIP_MEMORY_SCOPE_AGENT)
#define AST(P, V) __hip_atomic_store((P), (V), __ATOMIC_RELAXED, __HIP_MEMORY_SCOPE_AGENT)

__device__ __forceinline__ ushort_t bf16_rne(float f) {
  uint_t u = __float_as_uint(f);
  return (ushort_t)((u + 0x7fffu + ((u >> 16) & 1u)) >> 16);
}
__device__ __forceinline__ float bf16f(ushort_t h) {
  return __uint_as_float(((uint_t)h) << 16);
}
__device__ __forceinline__ int gRow(int rs, int m) {
  int base = m * NJ;
  if (rs < 32) return base + rs;
  if (rs < 64) return 512 + base + (rs - 32);
  return 1024 + base + (rs - 64);
}

template <bool LO>
__device__ __forceinline__ void loadW(short8* dst, const float* __restrict__ W,
                                      int tile, int m, int lane) {
  int rs = tile * 16 + (lane & 15);
  const float* p = W + (size_t)gRow(rs, m) * 512 + ((lane >> 4) << 3);
#pragma unroll
  for (int c = 0; c < 16; ++c) {
    const float* pc = p + c * 32;
    short8 o;
#pragma unroll
    for (int i = 0; i < 8; ++i) {
      float v = pc[i];
      ushort_t hi = bf16_rne(v);
      o[i] = LO ? (short)bf16_rne(v - bf16f(hi)) : (short)hi;
    }
    dst[c] = o;
  }
}

__global__ __launch_bounds__(TPB, 1) void gru_kernel(
    const float* __restrict__ x, const float* __restrict__ Wih,
    const float* __restrict__ Whh, const float* __restrict__ bih,
    const float* __restrict__ bhh, float* __restrict__ out,
    uint_t* __restrict__ wsp, int NT) {
  __shared__ __align__(16) uint_t s_pb[4096];  // 16KB: 16 chunks x 1KB (hi)
  __shared__ __align__(16) uint_t s_xlo[4096]; // 16KB: x lo-planes (gi only)
  __shared__ float s_gi[96 * 17];
  __shared__ float s_gh[96 * 17];
  __shared__ float s_hloc[NB * NJ]; // own h slice, f32 across steps
  __shared__ float s_bhh[NJ];
  __shared__ int s_stop;

  const int tid = threadIdx.x;
  const int lane = tid & 63;
  const int w = tid >> 6;
  const int bid = blockIdx.x;
  const int g = bid & 15; // same-XCD-leaning group mapping (perf only)
  const int m = bid >> 4;
  const int me = (g << 4) + m;
  if (NT <= 0) return;

  uint_t* flags = wsp;
  uint_t* gbuf = wsp + GBUF_BASE;

  // ---- stage relu(x) as hi plane (s_pb) + lo plane (s_xlo) ----
  for (int i = tid; i < 1024; i += TPB) {
    int b = i >> 6, k0 = (i & 63) << 3;
    const float* px = x + (size_t)(g * NB + b) * 512 + k0;
    u32x4 vh, vl;
#pragma unroll
    for (int jj = 0; jj < 4; ++jj) {
      float f0 = px[2 * jj], f1 = px[2 * jj + 1];
      f0 = f0 > 0.f ? f0 : 0.f;
      f1 = f1 > 0.f ? f1 : 0.f;
      ushort_t h0 = bf16_rne(f0), h1 = bf16_rne(f1);
      vh[jj] = (uint_t)h0 | ((uint_t)h1 << 16);
      vl[jj] = (uint_t)bf16_rne(f0 - bf16f(h0)) |
               ((uint_t)bf16_rne(f1 - bf16f(h1)) << 16);
    }
    int c = k0 >> 5, kk = k0 & 31;
    int base = c * 1024 + ((((b << 6) + (kk << 1))) ^ ((b & 7) << 4));
    *(u32x4*)((char*)s_pb + base) = vh;
    *(u32x4*)((char*)s_xlo + base) = vl;
  }
  if (tid < NJ) s_bhh[tid] = bhh[1024 + m * NJ + tid];
  if (tid == 0) s_stop = 0;
  __syncthreads();

  short8 wA[16], wB[16];
  const f32x4 vzero = {0.f, 0.f, 0.f, 0.f};
  const int bcol = lane & 15;
  const int roff = ((bcol << 6) + ((lane >> 4) << 4)) ^ ((bcol & 7) << 4);
  const char* pb = (const char*)s_pb;
  const char* pxl = (const char*)s_xlo;

  // ---- gi = relu(x) @ W_ih^T (3-term hi/lo split) ----
  f32x4 acc0 = vzero, acc1 = vzero;
  if (w < 3) {
    loadW<false>(wA, Wih, 2 * w, m, lane);
    loadW<false>(wB, Wih, 2 * w + 1, m, lane);
    {
      f32x4 a0h = vzero, a0l = vzero, a1h = vzero, a1l = vzero;
#pragma unroll
      for (int c = 0; c < 16; ++c) {
        short8 bh = *(const short8*)(pb + c * 1024 + roff);
        short8 bl = *(const short8*)(pxl + c * 1024 + roff);
        a0h = __builtin_amdgcn_mfma_f32_16x16x32_bf16(wA[c], bh, a0h, 0, 0, 0);
        a1h = __builtin_amdgcn_mfma_f32_16x16x32_bf16(wB[c], bh, a1h, 0, 0, 0);
        a0l = __builtin_amdgcn_mfma_f32_16x16x32_bf16(wA[c], bl, a0l, 0, 0, 0);
        a1l = __builtin_amdgcn_mfma_f32_16x16x32_bf16(wB[c], bl, a1l, 0, 0, 0);
      }
      acc0 = a0h + a0l;
      acc1 = a1h + a1l;
    }
    loadW<true>(wA, Wih, 2 * w, m, lane);
    loadW<true>(wB, Wih, 2 * w + 1, m, lane);
#pragma unroll
    for (int c = 0; c < 16; ++c) {
      short8 bh = *(const short8*)(pb + c * 1024 + roff);
      acc0 = __builtin_amdgcn_mfma_f32_16x16x32_bf16(wA[c], bh, acc0, 0, 0, 0);
      acc1 = __builtin_amdgcn_mfma_f32_16x16x32_bf16(wB[c], bh, acc1, 0, 0, 0);
    }
  }
  __syncthreads();
  if (w < 3) {
    int drow = (lane >> 4) << 2;
#pragma unroll
    for (int q = 0; q < 4; ++q) {
      int rs0 = 2 * w * 16 + drow + q, rs1 = rs0 + 16;
      int g0 = gRow(rs0, m), g1 = gRow(rs1, m);
      s_gi[rs0 * 17 + bcol] = acc0[q] + bih[g0] + (rs0 < 64 ? bhh[g0] : 0.f);
      s_gi[rs1 * 17 + bcol] = acc1[q] + bih[g1] + (rs1 < 64 ? bhh[g1] : 0.f);
    }
    loadW<false>(wA, Whh, 2 * w, m, lane); // W_hh resident from here
    loadW<false>(wB, Whh, 2 * w + 1, m, lane);
  }
  for (int i = tid; i < 4096; i += TPB) s_pb[i] = 0u; // h0 = 0
  for (int i = tid; i < NB * NJ; i += TPB) s_hloc[i] = 0.f;
  __syncthreads();

  const size_t outRow = (size_t)NT * 512;
  float* outBase = out + (size_t)(g * NB) * outRow + m * NJ;

  for (int t = 0; t < NT; ++t) {
    // ---- phase 1: gh = W_hh @ h_hi from LDS chunks (waves 0-2) ----
    if (w < 3) {
      f32x4 aE0 = vzero, aO0 = vzero, aE1 = vzero, aO1 = vzero;
#pragma unroll
      for (int p = 0; p < 16; p += 2) {
        short8 b0 = *(const short8*)(pb + p * 1024 + roff);
        short8 b1 = *(const short8*)(pb + (p + 1) * 1024 + roff);
        aE0 = __builtin_amdgcn_mfma_f32_16x16x32_bf16(wA[p], b0, aE0, 0, 0, 0);
        aE1 = __builtin_amdgcn_mfma_f32_16x16x32_bf16(wB[p], b0, aE1, 0, 0, 0);
        aO0 = __builtin_amdgcn_mfma_f32_16x16x32_bf16(wA[p + 1], b1, aO0, 0, 0, 0);
        aO1 = __builtin_amdgcn_mfma_f32_16x16x32_bf16(wB[p + 1], b1, aO1, 0, 0, 0);
      }
      f32x4 r0 = aE0 + aO0, r1 = aE1 + aO1;
      int drow = (lane >> 4) << 2;
#pragma unroll
      for (int q = 0; q < 4; ++q) {
        s_gh[(2 * w * 16 + drow + q) * 17 + bcol] = r0[q];
        s_gh[((2 * w + 1) * 16 + drow + q) * 17 + bcol] = r1[q];
      }
    }
    __syncthreads();

    // ---- phase 2: gates on waves 4-5 (4 elems/thread); export hi u64 ----
    const int et = tid - 256; // [0,128) for waves 4-5
    float hn[4];
    int eb_ = 0, ej0 = 0;
    if (et >= 0) {
      int b = et >> 3, j0 = (et & 7) << 2;
      eb_ = b;
      ej0 = j0;
#pragma unroll
      for (int e = 0; e < 4; ++e) {
        int j = j0 + e;
        float pr = s_gi[j * 17 + b] + s_gh[j * 17 + b];
        float pz = s_gi[(32 + j) * 17 + b] + s_gh[(32 + j) * 17 + b];
        float r = 1.f / (1.f + __expf(-pr));
        float z = 1.f / (1.f + __expf(-pz));
        float pn =
            s_gi[(64 + j) * 17 + b] + r * (s_gh[(64 + j) * 17 + b] + s_bhh[j]);
        float n = 1.f - 2.f / (1.f + __expf(2.f * pn));
        hn[e] = n + z * (s_hloc[b * 32 + j] - n);
        s_hloc[b * 32 + j] = hn[e];
      }
      uint_t w0 = (uint_t)bf16_rne(hn[0]) | ((uint_t)bf16_rne(hn[1]) << 16);
      uint_t w1 = (uint_t)bf16_rne(hn[2]) | ((uint_t)bf16_rne(hn[3]) << 16);
      u64_t pq = (u64_t)w0 | ((u64_t)w1 << 32);
      u64_t* eb64 =
          (u64_t*)(gbuf + (size_t)((t & 1) ^ 1) * BUF_U32 + g * GRP_U32);
      __hip_atomic_store(eb64 + (m << 7) + (eb_ << 3) + (et & 7), pq,
                         __ATOMIC_RELAXED, __HIP_MEMORY_SCOPE_AGENT);
    }
    __syncthreads(); // drains exports (out not yet issued)

    if (tid == 256) // flag ASAP after the drain
      AST(&flags[me << 5], (uint_t)(t + 1));
    if (et >= 0) { // out store overlaps the poll window
      f32x4 ov = {hn[0], hn[1], hn[2], hn[3]};
      __builtin_nontemporal_store(
          ov,
          (f32x4*)(outBase + (size_t)eb_ * outRow + (size_t)t * 512 + ej0));
    }
    // ---- fused poll+reload: wave w (<4) owns peers 4w..4w+3 ----
    if (w < 4 && t + 1 < NT) {
      const uint_t tgt = (uint_t)(t + 1);
      int ok = 1;
      {
        uint_t sp = 0;
        uint_t* fp = flags + (((g << 4) + (w << 2) + (lane & 3)) << 5);
        for (;;) {
          uint_t v = tgt;
          if (lane < 4) v = ALD(fp);
          if (__all((int)(v >= tgt))) break;
          ++sp;
          uint_t ab = 0;
          if ((sp & 127u) == 0u) {
            ab = ALD(&flags[ABORT_IDX]);
            if (sp > SPIN_MAX) {
              AST(&flags[ABORT_IDX], 1u);
              ab = 1;
            }
          }
          if (__any((int)(ab != 0))) {
            if (lane == 0) s_stop = 1;
            ok = 0;
            break;
          }
          __builtin_amdgcn_s_sleep(1);
        }
      }
      if (ok) { // reload this wave's 4 peers: 8 u64/lane, batched
        const u64_t* srcq =
            (const u64_t*)(gbuf + (size_t)((t + 1) & 1) * BUF_U32 +
                           g * GRP_U32) +
            (w << 9);
#define LDI(k)                                                                 \
  __hip_atomic_load(srcq + lane + ((k) << 6), __ATOMIC_RELAXED,                \
                    __HIP_MEMORY_SCOPE_AGENT)
        u64_t q0 = LDI(0), q1 = LDI(1), q2 = LDI(2), q3 = LDI(3);
        u64_t q4 = LDI(4), q5 = LDI(5), q6 = LDI(6), q7 = LDI(7);
#undef LDI
#define STI(k, qq)                                                             \
  {                                                                            \
    uint_t qb = (uint_t)(((w << 9) + lane + ((k) << 6)) << 3);                 \
    *(u64_t*)((char*)s_pb + (qb ^ (((qb >> 6) & 7u) << 4))) = (qq);            \
  }
        STI(0, q0) STI(1, q1) STI(2, q2) STI(3, q3)
        STI(4, q4) STI(5, q5) STI(6, q6) STI(7, q7)
#undef STI
      }
    }
    __syncthreads();
    if (s_stop) break;
  }
}

extern "C" void kernel_launch(void* const* d_in, const int* in_sizes, int n_in,
                              void* d_out, int out_size, void* d_ws,
                              size_t ws_size, hipStream_t stream) {
  const float* x = (const float*)d_in[0];
  const float* Wih = (const float*)d_in[1];
  const float* Whh = (const float*)d_in[2];
  const float* bih = (const float*)d_in[3];
  const float* bhh = (const float*)d_in[4];
  float* out = (float*)d_out;
  int NT = out_size / (256 * 512);
  // ws: [0,64KB) flags (128B-spaced) + abort; data @64KB: 2 x 256KB (hi only)
  uint_t* wsp = (uint_t*)d_ws;
  (void)hipMemsetAsync(d_ws, 0, 65536, stream);
  hipLaunchKernelGGL(gru_kernel, dim3(NG * NM), dim3(TPB), 0, stream, x, Wih,
                     Whh, bih, bhh, out, wsp, NT);
}